// Round 9
// baseline (152.901 us; speedup 1.0000x reference)
//
#include <hip/hip_runtime.h>

// TileRenderer: out[p,b,y,x] = sum_s bilinear_sample(sources[p,s,b], affine(locs[p,s]))
// n_ptiles=1024, max_src=4, n_bands=5, ptile_slen=52.
//
// Affine (exact): l = (loc*(4/52) + 24/52 - 0.5)*2
//   ix = x*(25.5/26) + (1-l1)*25.5 - 25.5^2/26   (grid[...,0] uses swapped l)
//   iy = y*(25.5/26) + (1-l0)*25.5 - 25.5^2/26
//
// Round-9 decomposition: block = (ptile, 13-row strip). The sampling geometry
// is band-independent, so per source it is computed ONCE (12 regs) and reused
// across the 5 bands -> per-px-band VALU drops ~24 -> ~9. A 13-row output
// strip needs only 14 source rows (12*A + 2 taps), so a slice buffer is
// 736 floats; 2-buffer ring = 5.9 KB LDS -> occupancy is wave-capped
// (8 blocks/CU, 32 waves). Sync = round-6's proven pattern (syncthreads;
// stage next slice; compute), 20 phases (4 src x 5 bands).
// y handled pad-free via zeroed pad rows; x via the clamp[-1,51]+mask trick
// (FPAD keeps reads in-bounds; pads are zeroed so masked taps stay finite).
constexpr int NP = 1024;
constexpr int MS = 4;
constexpr int NB = 5;
constexpr int SL = 52;
constexpr int SS = SL * SL;        // 2704
constexpr int NTHR = 256;
constexpr int RPB = 13;            // output rows per block (tile split in 4)
constexpr int PXB = RPB * SL;      // 676 px per (block, band)
constexpr int NJ  = 3;             // ceil(676/256)
constexpr int SROWS = 14;          // staged source rows per slice
constexpr int FPAD = 4;            // front/tail pad floats (zeroed)
constexpr int BUFF = FPAD + SROWS * SL + FPAD;   // 736 floats
constexpr int NPH = MS * NB;       // 20 phases

__device__ __forceinline__ void gload_lds16(const float* g, float* l) {
    __builtin_amdgcn_global_load_lds(
        (const __attribute__((address_space(1))) void*)g,
        (__attribute__((address_space(3))) void*)l,
        16, 0, 0);
}

__global__ __launch_bounds__(NTHR) void tile_render_kernel(
    const float* __restrict__ locs,
    const float* __restrict__ sources,
    float* __restrict__ out)
{
    __shared__ __align__(16) float smem[2 * BUFF];   // 5888 B

    const int blk = blockIdx.x;
    const int p = blk >> 2;
    const int h = blk & 3;          // row-strip index: rows 13h..13h+12
    const int tid = threadIdx.x;

    const float A = 25.5f / 26.0f;
    float bx[MS], byr[MS];
    int gsa[MS], topa[MS], cnta[MS];
    #pragma unroll
    for (int s = 0; s < MS; ++s) {
        float loc0 = locs[(p * MS + s) * 2 + 0];
        float loc1 = locs[(p * MS + s) * 2 + 1];
        float l0 = (loc0 * (4.0f / 52.0f) + (24.0f / 52.0f) - 0.5f) * 2.0f;
        float l1 = (loc1 * (4.0f / 52.0f) + (24.0f / 52.0f) - 0.5f) * 2.0f;
        bx[s] = (1.0f - l1) * 25.5f - 25.5f * 25.5f / 26.0f;
        float by = (1.0f - l0) * 25.5f - 25.5f * 25.5f / 26.0f;
        float byh = fmaf((float)(RPB * h), A, by);   // fold strip offset
        int r0 = (int)floorf(byh);    // lowest tap row for this strip/source
        byr[s] = byh - (float)r0;     // floor(y*A+byr) = tap row - r0 directly
        int gs = max(r0, 0);
        int ge = min(r0 + SROWS - 1, SL - 1);
        gsa[s] = gs;                  // first staged global row
        topa[s] = gs - r0;            // zeroed pad rows on top (0..2)
        cnta[s] = ge - gs + 1;        // staged rows (12..14)
    }

    // Per-thread output pixels (j=NJ-1 dummy-safe for tid >= 164).
    int xs_[NJ], obase[NJ];
    float yls[NJ];
    #pragma unroll
    for (int j = 0; j < NJ; ++j) {
        int px = tid + j * NTHR;
        int pv = (px < PXB) ? px : 0;
        int yl = pv / SL;
        int x = pv - yl * SL;
        xs_[j] = x;
        yls[j] = (float)yl;
        obase[j] = (RPB * h + yl) * SL + x;
    }

    const float* gtile = sources + (size_t)p * (MS * NB * SS);

    auto stage = [&](int s2, int b2, float* slot) {
        int top = topa[s2], cnt = cnta[s2];
        // zero pad rows + FPADs (disjoint from DMA interior; every masked or
        // pad-row read must land on finite data)
        if (tid < top * SL) slot[FPAD + tid] = 0.0f;
        int bo = FPAD + (top + cnt) * SL;
        if (tid < (FPAD + SROWS * SL - bo)) slot[bo + tid] = 0.0f;
        if (tid < FPAD) { slot[tid] = 0.0f; slot[FPAD + SROWS * SL + tid] = 0.0f; }
        // DMA the interior: cnt*52 contiguous floats, 16B-aligned both sides
        if (tid < cnt * (SL / 4)) {
            const float* g = gtile + ((size_t)s2 * NB + b2) * SS + gsa[s2] * SL + 4 * tid;
            gload_lds16(g, slot + FPAD + top * SL + 4 * tid);
        }
    };

    float acc[NJ][NB];
    #pragma unroll
    for (int j = 0; j < NJ; ++j)
        #pragma unroll
        for (int b = 0; b < NB; ++b) acc[j][b] = 0.0f;

    stage(0, 0, smem);   // phase 0 -> slot 0

    #pragma unroll
    for (int s = 0; s < MS; ++s) {
        // ---- geometry: once per source, reused by all 5 bands ----
        int adr[NJ];
        float wxa[NJ], wxb[NJ], wwy[NJ];
        #pragma unroll
        for (int j = 0; j < NJ; ++j) {
            float ix = fmaf((float)xs_[j], A, bx[s]);
            float ixf = floorf(ix);
            float wx = ix - ixf;
            int xi = (int)ixf;
            wxa[j] = ((unsigned)xi       <= 51u) ? (1.0f - wx) : 0.0f;
            wxb[j] = ((unsigned)(xi + 1) <= 51u) ? wx          : 0.0f;
            int xc = min(max(xi, -1), SL - 1);
            float iy = fmaf(yls[j], A, byr[s]);
            float iyf = floorf(iy);
            wwy[j] = iy - iyf;
            int k = (int)iyf;                 // local tap row, 0..12
            adr[j] = k * SL + xc + FPAD;
        }
        #pragma unroll
        for (int b = 0; b < NB; ++b) {
            const int i = NB * s + b;
            // Barrier: drains vmcnt -> slice i ready; previous compute done
            // -> restaging the other slot is safe. (Round-6 proven pattern.)
            __syncthreads();
            if (i + 1 < NPH)
                stage((i + 1) / NB, (i + 1) % NB, smem + ((i + 1) & 1) * BUFF);
            const float* cur = smem + (i & 1) * BUFF;
            #pragma unroll
            for (int j = 0; j < NJ; ++j) {
                const float* q = cur + adr[j];
                float v00 = q[0],  v01 = q[1];        // ds_read2_b32
                float v10 = q[SL], v11 = q[SL + 1];   // ds_read2_b32
                float h0 = fmaf(v01, wxb[j], v00 * wxa[j]);
                float h1 = fmaf(v11, wxb[j], v10 * wxa[j]);
                acc[j][b] = fmaf(wwy[j], h1 - h0, h0 + acc[j][b]);
            }
        }
    }

    float* op = out + (size_t)p * (NB * SS);
    #pragma unroll
    for (int j = 0; j < NJ; ++j) {
        if (tid + j * NTHR < PXB) {
            #pragma unroll
            for (int b = 0; b < NB; ++b)
                __builtin_nontemporal_store(acc[j][b], op + b * SS + obase[j]);
        }
    }
}

extern "C" void kernel_launch(void* const* d_in, const int* in_sizes, int n_in,
                              void* d_out, int out_size, void* d_ws, size_t ws_size,
                              hipStream_t stream) {
    const float* locs = (const float*)d_in[0];
    const float* sources = (const float*)d_in[1];
    float* out = (float*)d_out;
    dim3 grid(NP * 4);
    dim3 block(NTHR);
    hipLaunchKernelGGL(tile_render_kernel, grid, block, 0, stream,
                       locs, sources, out);
}

// Round 10
// 48.261 us; speedup vs baseline: 3.1682x; 3.1682x over previous
//
#include <hip/hip_runtime.h>

// TileRenderer: out[p,b,y,x] = sum_s bilinear_sample(sources[p,s,b], affine(locs[p,s]))
// n_ptiles=1024, max_src=4, n_bands=5, ptile_slen=52.
//
// Affine (exact): l = (loc*(4/52) + 24/52 - 0.5)*2
//   ix = x*(25.5/26) + (1-l1)*25.5 - 25.5^2/26   (grid[...,0] uses swapped l)
//   iy = y*(25.5/26) + (1-l0)*25.5 - 25.5^2/26
// For locs in [0,1]: floor(ix), floor(iy) in [-2,52].
//
// Structure = round-8 (proven 47.4us): global_load_lds staging into y-padded
// linear LDS (rows -2..53, interior contiguous, 16B-aligned at float 108),
// double-buffer, one barrier per source, nt output stores.
// ONE change (round-10): VERTICAL PIXEL PAIRS. Each thread owns (y=2k, x) and
// (y=2k+1, x). The pair shares the full x-side geometry, and since A<1 the
// two pixels' tap rows are covered by {r, r+1, r+2} where r=floor(iy1):
// 3 ds_read2_b32 off one vaddr (offsets 0/1, 52/53, 104/105) replace 4.
// Edge r=52: base=min(r,51) keeps reads inside the 56-row buffer; the
// tap-pair selection clamp substitutes pad-zero rows exactly when the true
// taps are out-of-image (result 0 either way).
constexpr int NP = 1024;
constexpr int MS = 4;
constexpr int NB = 5;
constexpr int SL = 52;
constexpr int SS = SL * SL;     // 2704
constexpr int NTHR = 256;
constexpr int NPAIR = SS / 2;   // 1352 vertical pairs
constexpr int NJ = 6;           // ceil(1352/256)
constexpr int PTAIL = NPAIR - (NJ - 1) * NTHR;  // 72
constexpr int NCH = SS / 4;     // 676 float4 chunks
constexpr int FPAD = 4;         // front/tail pad (floats)
constexpr int PY = 2;           // zero pad rows above/below (rows -2..53)
constexpr int BUFF = FPAD + (SL + 2 * PY) * SL + FPAD;  // 2920 floats
constexpr int INT0 = FPAD + PY * SL;  // 108: interior row0col0; 432B, 16B-mult

__device__ __forceinline__ void gload_lds16(const float* g, float* l) {
    __builtin_amdgcn_global_load_lds(
        (const __attribute__((address_space(1))) void*)g,
        (__attribute__((address_space(3))) void*)l,
        16, 0, 0);
}

__global__ __launch_bounds__(NTHR) void tile_render_kernel(
    const float* __restrict__ locs,
    const float* __restrict__ sources,
    float* __restrict__ out)
{
    __shared__ __align__(16) float smem[2 * BUFF];  // 23360 B -> 7 blocks/CU

    const int blk = blockIdx.x;
    const int p = blk / NB;
    const int b = blk - p * NB;
    const int tid = threadIdx.x;

    // Zero both buffers (pads must be genuine zeros; interior re-staged).
    for (int i = 4 * tid; i < 2 * BUFF; i += 4 * NTHR)
        *reinterpret_cast<float4*>(smem + i) = make_float4(0.f, 0.f, 0.f, 0.f);

    const float A = 25.5f / 26.0f;
    float bx[MS], by[MS];
    #pragma unroll
    for (int s = 0; s < MS; ++s) {
        float loc0 = locs[(p * MS + s) * 2 + 0];
        float loc1 = locs[(p * MS + s) * 2 + 1];
        float l0 = (loc0 * (4.0f / 52.0f) + (24.0f / 52.0f) - 0.5f) * 2.0f;
        float l1 = (loc1 * (4.0f / 52.0f) + (24.0f / 52.0f) - 0.5f) * 2.0f;
        bx[s] = (1.0f - l1) * 25.5f - 25.5f * 25.5f / 26.0f;
        by[s] = (1.0f - l0) * 25.5f - 25.5f * 25.5f / 26.0f;
    }

    // Hoisted per-thread pair coords: pair pp -> (x = pp%52, y1 = 2*(pp/52)).
    // j = NJ-1 dummy-safe for tid >= PTAIL.
    float fxv[NJ], fyv[NJ];
    #pragma unroll
    for (int j = 0; j < NJ; ++j) {
        int pp = tid + j * NTHR;
        if (pp >= NPAIR) pp = 0;
        int yp = pp / SL;
        fxv[j] = (float)(pp - yp * SL);
        fyv[j] = (float)(2 * yp);
    }

    const float* gsrc = sources + ((size_t)p * MS * NB + b) * SS;
    auto stage = [&](float* buf, int s) {
        const float* g = gsrc + (size_t)s * (NB * SS);
        float* dst = buf + INT0;
        gload_lds16(g + 4 * tid,          dst + 4 * tid);
        gload_lds16(g + 4 * (tid + NTHR), dst + 4 * (tid + NTHR));
        if (tid < NCH - 2 * NTHR)
            gload_lds16(g + 4 * (tid + 2 * NTHR), dst + 4 * (tid + 2 * NTHR));
    };

    float acc0[NJ], acc1[NJ];
    #pragma unroll
    for (int j = 0; j < NJ; ++j) { acc0[j] = 0.0f; acc1[j] = 0.0f; }

    __syncthreads();        // zero-init visible before staging overwrites
    stage(smem, 0);

    #pragma unroll
    for (int s = 0; s < MS; ++s) {
        // Barrier drains vmcnt: buffer for s is ready; all reads of the
        // other buffer (s-1's compute) are done, so restaging is safe.
        __syncthreads();
        if (s < MS - 1) stage(smem + ((s + 1) & 1) * BUFF, s + 1);

        const float* cur = smem + (s & 1) * BUFF;
        const float bxs = bx[s], bys = by[s];
        #pragma unroll
        for (int j = 0; j < NJ; ++j) {
            // ---- x-side: once per pair ----
            float ix = fmaf(fxv[j], A, bxs);
            float ixf = floorf(ix);
            float wx = ix - ixf;
            int xi = (int)ixf;
            float wxa = ((unsigned)xi       <= 51u) ? (1.0f - wx) : 0.0f;
            float wxb = ((unsigned)(xi + 1) <= 51u) ? wx          : 0.0f;
            int xc = min(max(xi, -1), SL - 1);
            // ---- y-side: two pixels ----
            float iy1 = fmaf(fyv[j],        A, bys);
            float iy2 = fmaf(fyv[j] + 1.0f, A, bys);
            float f1 = floorf(iy1), f2 = floorf(iy2);
            float wy1 = iy1 - f1,   wy2 = iy2 - f2;
            int r  = (int)f1;
            int r2 = (int)f2;                 // r or r+1
            int base = min(r, SL - 1);        // keep 3-row window in buffer
            bool o1 = (r != base);            // true only when r == 52
            bool o2 = (r2 - base >= 1);       // tap-pair select (clamped)
            const float* q = cur + (base * SL + (xc + INT0));
            float a0 = q[0],       a1 = q[1];        // ds_read2_b32 0/1
            float b0 = q[SL],      b1 = q[SL + 1];   // ds_read2_b32 52/53
            float c0 = q[2 * SL],  c1 = q[2 * SL + 1];  // ds_read2_b32 104/105
            float h0 = fmaf(a1, wxb, a0 * wxa);
            float h1 = fmaf(b1, wxb, b0 * wxa);
            float h2 = fmaf(c1, wxb, c0 * wxa);
            float p1lo = o1 ? h1 : h0, p1hi = o1 ? h2 : h1;
            float p2lo = o2 ? h1 : h0, p2hi = o2 ? h2 : h1;
            acc0[j] = fmaf(wy1, p1hi - p1lo, p1lo + acc0[j]);
            acc1[j] = fmaf(wy2, p2hi - p2lo, p2lo + acc1[j]);
        }
    }

    float* outp = out + ((size_t)p * NB + b) * SS;
    #pragma unroll
    for (int j = 0; j < NJ; ++j) {
        if (j < NJ - 1 || tid < PTAIL) {
            int x = (int)fxv[j];
            int o = (int)fyv[j] * SL + x;
            __builtin_nontemporal_store(acc0[j], outp + o);
            __builtin_nontemporal_store(acc1[j], outp + o + SL);
        }
    }
}

extern "C" void kernel_launch(void* const* d_in, const int* in_sizes, int n_in,
                              void* d_out, int out_size, void* d_ws, size_t ws_size,
                              hipStream_t stream) {
    const float* locs = (const float*)d_in[0];
    const float* sources = (const float*)d_in[1];
    float* out = (float*)d_out;
    dim3 grid(NP * NB);
    dim3 block(NTHR);
    hipLaunchKernelGGL(tile_render_kernel, grid, block, 0, stream,
                       locs, sources, out);
}

// Round 12
// 47.086 us; speedup vs baseline: 3.2473x; 1.0249x over previous
//
#include <hip/hip_runtime.h>

// TileRenderer: out[p,b,y,x] = sum_s bilinear_sample(sources[p,s,b], affine(locs[p,s]))
// n_ptiles=1024, max_src=4, n_bands=5, ptile_slen=52.
//
// Affine (exact): l = (loc*(4/52) + 24/52 - 0.5)*2
//   ix = x*(25.5/26) + (1-l1)*25.5 - 25.5^2/26   (grid[...,0] uses swapped l)
//   iy = y*(25.5/26) + (1-l0)*25.5 - 25.5^2/26
// For locs in [0,1]: floor(ix), floor(iy) in [-2,52].
//
// FINAL = round-8 (proven 47.4 us, passing): global_load_lds staging into a
// y-padded linear LDS buffer (rows -2..53, interior one contiguous
// 2704-float block at float offset 108), double-buffer, one barrier per
// source, row-major pixel-per-lane compute, non-temporal output stores
// (output is write-once/never-read; keeping it out of L3 preserves input
// residency: working set 221 MB input + 54 MB output vs 256 MB L3).
//
// Session record: R7 (column-strip), R9 (band-reuse strips), R10 (vertical
// pairs), R11 (persistent blocks) — every multi-delta restructure either
// regressed (VGPR/occupancy collapse, bank conflicts) or raced; the
// issue-side levers each moved <=1.5 us. This structure is the measured
// plateau: ~277 MB coherent traffic/call at ~5.9 TB/s effective (~93% of
// the 6.3 TB/s achievable ceiling), compute/LDS issue hidden beneath.
constexpr int NP = 1024;
constexpr int MS = 4;
constexpr int NB = 5;
constexpr int SL = 52;
constexpr int SS = SL * SL;     // 2704
constexpr int NTHR = 256;
constexpr int NJ = 11;          // ceil(SS/256)
constexpr int TAIL = SS - (NJ - 1) * NTHR;  // 144
constexpr int NCH = SS / 4;     // 676 float4 chunks
constexpr int FPAD = 4;         // front/tail pad (floats)
constexpr int PY = 2;           // zero pad rows above/below
constexpr int BUFF = FPAD + (SL + 2 * PY) * SL + FPAD;  // 4+2912+4 = 2920
constexpr int INT0 = FPAD + PY * SL;  // 108: interior (row0,col0); 432B, 16B-mult

__device__ __forceinline__ void gload_lds16(const float* g, float* l) {
    __builtin_amdgcn_global_load_lds(
        (const __attribute__((address_space(1))) void*)g,
        (__attribute__((address_space(3))) void*)l,
        16, 0, 0);
}

__global__ __launch_bounds__(NTHR) void tile_render_kernel(
    const float* __restrict__ locs,
    const float* __restrict__ sources,
    float* __restrict__ out)
{
    __shared__ __align__(16) float smem[2 * BUFF];  // 23360 B -> 7 blocks/CU

    const int blk = blockIdx.x;
    const int p = blk / NB;
    const int b = blk - p * NB;
    const int tid = threadIdx.x;

    // Zero both buffers (pads must be genuine zeros; interior re-staged).
    for (int i = 4 * tid; i < 2 * BUFF; i += 4 * NTHR)
        *reinterpret_cast<float4*>(smem + i) = make_float4(0.f, 0.f, 0.f, 0.f);

    const float A = 25.5f / 26.0f;
    float bx[MS], by[MS];
    #pragma unroll
    for (int s = 0; s < MS; ++s) {
        float loc0 = locs[(p * MS + s) * 2 + 0];
        float loc1 = locs[(p * MS + s) * 2 + 1];
        float l0 = (loc0 * (4.0f / 52.0f) + (24.0f / 52.0f) - 0.5f) * 2.0f;
        float l1 = (loc1 * (4.0f / 52.0f) + (24.0f / 52.0f) - 0.5f) * 2.0f;
        bx[s] = (1.0f - l1) * 25.5f - 25.5f * 25.5f / 26.0f;
        by[s] = (1.0f - l0) * 25.5f - 25.5f * 25.5f / 26.0f;
    }

    // Hoisted per-thread pixel coords (j = NJ-1 dummy-safe for tid >= TAIL).
    float fx[NJ], fy[NJ];
    #pragma unroll
    for (int j = 0; j < NJ; ++j) {
        int pix = tid + j * NTHR;
        if (pix >= SS) pix = 0;
        int y = pix / SL;
        fx[j] = (float)(pix - y * SL);
        fy[j] = (float)y;
    }

    const float* gsrc = sources + ((size_t)p * MS * NB + b) * SS;
    auto stage = [&](float* buf, int s) {
        const float* g = gsrc + (size_t)s * (NB * SS);
        float* dst = buf + INT0;
        gload_lds16(g + 4 * tid,          dst + 4 * tid);
        gload_lds16(g + 4 * (tid + NTHR), dst + 4 * (tid + NTHR));
        if (tid < NCH - 2 * NTHR)
            gload_lds16(g + 4 * (tid + 2 * NTHR), dst + 4 * (tid + 2 * NTHR));
    };

    float acc[NJ];
    #pragma unroll
    for (int j = 0; j < NJ; ++j) acc[j] = 0.0f;

    __syncthreads();        // zero-init visible before staging overwrites
    stage(smem, 0);

    #pragma unroll
    for (int s = 0; s < MS; ++s) {
        // Barrier drains vmcnt: buffer for s is ready; all reads of the
        // other buffer (s-1's compute) are also done, so restaging is safe.
        __syncthreads();
        if (s < MS - 1) stage(smem + ((s + 1) & 1) * BUFF, s + 1);

        const float* cur = smem + (s & 1) * BUFF;
        const float bxs = bx[s], bys = by[s];
        #pragma unroll
        for (int j = 0; j < NJ; ++j) {
            float ix = fmaf(fx[j], A, bxs);
            float iy = fmaf(fy[j], A, bys);
            float ixf = floorf(ix);
            float iyf = floorf(iy);
            float wx = ix - ixf;
            float wy = iy - iyf;
            int xi = (int)ixf;
            int yi = (int)iyf;
            float wx0 = 1.0f - wx;
            // x: zeros-padding folded into weights; tap base clamped so the
            // {xc, xc+1} pair covers every valid corner, OOB half masked.
            float wxa = ((unsigned)xi       <= 51u) ? wx0 : 0.0f;
            float wxb = ((unsigned)(xi + 1) <= 51u) ? wx  : 0.0f;
            int xc = min(max(xi, -1), SL - 1);
            // y: no mask, no clamp — pad rows are zeros; r1 = r0 + 52 static.
            const float* q = cur + (yi * SL + (xc + INT0));
            float v00 = q[0],  v01 = q[1];        // ds_read2_b32
            float v10 = q[SL], v11 = q[SL + 1];   // ds_read2_b32
            float h0 = fmaf(v01, wxb, v00 * wxa);
            float h1 = fmaf(v11, wxb, v10 * wxa);
            acc[j] = fmaf(wy, h1 - h0, h0 + acc[j]);
        }
    }

    float* outp = out + ((size_t)p * NB + b) * SS;
    #pragma unroll
    for (int j = 0; j < NJ; ++j) {
        int pix = tid + j * NTHR;
        if (j < NJ - 1 || tid < TAIL)
            __builtin_nontemporal_store(acc[j], outp + pix);
    }
}

extern "C" void kernel_launch(void* const* d_in, const int* in_sizes, int n_in,
                              void* d_out, int out_size, void* d_ws, size_t ws_size,
                              hipStream_t stream) {
    const float* locs = (const float*)d_in[0];
    const float* sources = (const float*)d_in[1];
    float* out = (float*)d_out;
    dim3 grid(NP * NB);
    dim3 block(NTHR);
    hipLaunchKernelGGL(tile_render_kernel, grid, block, 0, stream,
                       locs, sources, out);
}